// Round 7
// baseline (157.337 us; speedup 1.0000x reference)
//
#include <hip/hip_runtime.h>
#include <hip/hip_bf16.h>
#include <math.h>

#define SEQ 4096
#define HD  64
#define NBATCH 4

#define EM1   1.71828182845904523536f
#define INVD5 (1.0f/(4096.f + 5.f*EM1))
#define INVD4 (1.0f/(4096.f + 4.f*EM1))
#define INVD3 (1.0f/(4096.f + 3.f*EM1))

typedef __attribute__((ext_vector_type(8))) short short8;
typedef __attribute__((ext_vector_type(4))) short short4v;
typedef __attribute__((ext_vector_type(4))) float f32x4;

__device__ __forceinline__ f32x4 mfma16(short8 a, short8 b, f32x4 c) {
    return __builtin_amdgcn_mfma_f32_16x16x32_bf16(a, b, c, 0, 0, 0);
}

__device__ __forceinline__ short bfs(float x) {
    __hip_bfloat16 h = __float2bfloat16(x);
    return *(short*)&h;
}

__device__ __forceinline__ float sf(short s) {
    __hip_bfloat16 h;
    *(short*)&h = s;
    return __bfloat162float(h);
}

__device__ __forceinline__ short8 pack8(float4 a, float4 b) {
    short8 r;
    r[0] = bfs(a.x); r[1] = bfs(a.y); r[2] = bfs(a.z); r[3] = bfs(a.w);
    r[4] = bfs(b.x); r[5] = bfs(b.y); r[6] = bfs(b.z); r[7] = bfs(b.w);
    return r;
}

__device__ __forceinline__ float b2f(__hip_bfloat16 h) { return __bfloat162float(h); }

#define WSTR 72   // padded W row stride in elems: 144 B -> 16B-aligned, 2-way banks

// ---------------------------------------------------------------------------
// Kernel 1: fused wpack+projm.  512 blocks x 512 thr (8 waves, one ROLE each):
//   wave = role*2 + rh,  role 0=q, 1=k, 2=v, 3=v-halo,  rh = row-half.
// Identical to the proven r6 version; block 0 additionally zeroes doneC[4]
// (visible to kernel 2 via the kernel boundary).
// ---------------------------------------------------------------------------
__global__ __launch_bounds__(512, 4) void projm_kernel(
    const float* __restrict__ feat,
    const float* __restrict__ Wq, const float* __restrict__ Wk,
    const float* __restrict__ Wv,
    const float* __restrict__ bq, const float* __restrict__ bk,
    const float* __restrict__ bv,
    __hip_bfloat16* __restrict__ qsb, float* __restrict__ kpart,
    float* __restrict__ vpart, __hip_bfloat16* __restrict__ Mpart,
    float* __restrict__ kedge, unsigned int* __restrict__ doneC)
{
    __shared__ __hip_bfloat16 WbL[3 * 64 * WSTR];
    __shared__ __hip_bfloat16 kT[64 * 40];    // [h][t-local 0..31]
    __shared__ __hip_bfloat16 vT[64 * 40];    // [h][idx 0..35] = t0-2 .. t0+33
    __shared__ __hip_bfloat16 lvt[64 * 40];   // locv5^T [h][t-local 0..31]
    __shared__ float kred[2][64];
    __shared__ float vred[2][64];

    const int tid  = threadIdx.x;
    const int wv   = tid >> 6, lane = tid & 63;
    const int rh   = wv & 1;            // row-half (16 rows)
    const int role = wv >> 1;           // 0:q 1:k 2:v 3:halo
    const int quad = lane >> 4, ln = lane & 15;
    const int R0 = blockIdx.x * 32;
    const int b  = R0 >> 12;
    const int t0 = R0 & (SEQ - 1);
    const int chunk = blockIdx.x & 127;

    if (blockIdx.x == 0 && tid < 4) doneC[tid] = 0;

    // A-fragments: roles 0-2 load this rh's 16 main rows (3x duplicate -> L1
    // hit); role 3 loads halo rows (lanes 0,1 only).
    short8 af0, af1;
    const bool hflag = (rh == 0) ? (t0 > 0) : (t0 < SEQ - 32);
    if (role < 3) {
        const float* fp = feat + (size_t)(R0 + rh * 16 + ln) * HD + quad * 8;
        af0 = pack8(*(const float4*)(fp),      *(const float4*)(fp + 4));
        af1 = pack8(*(const float4*)(fp + 32), *(const float4*)(fp + 36));
    } else {
        const int hrow = (rh == 0) ? (t0 - 2 + ln) : (t0 + 32 + ln);
        if (ln < 2 && hflag) {
            const float* fp = feat + ((size_t)(b << 12) + hrow) * HD + quad * 8;
            af0 = pack8(*(const float4*)(fp),      *(const float4*)(fp + 4));
            af1 = pack8(*(const float4*)(fp + 32), *(const float4*)(fp + 36));
        } else {
            #pragma unroll
            for (int j = 0; j < 8; ++j) { af0[j] = 0; af1[j] = 0; }
        }
    }

    // pack W into LDS (row-major [col][k], padded stride WSTR); 512 threads
    // -> 8 floats each per matrix
    {
        const int r = tid >> 3, c = (tid & 7) * 8;
        #pragma unroll
        for (int m = 0; m < 3; ++m) {
            const float* W = (m == 0) ? Wq : (m == 1) ? Wk : Wv;
            const float s = (m == 0) ? 0.125f : 1.f;
            const float* src = W + r * 64 + c;
            float4 a0 = *(const float4*)(src);
            float4 a1 = *(const float4*)(src + 4);
            a0.x*=s; a0.y*=s; a0.z*=s; a0.w*=s;
            a1.x*=s; a1.y*=s; a1.z*=s; a1.w*=s;
            *(short8*)(WbL + m * 64 * WSTR + r * WSTR + c) = pack8(a0, a1);
        }
    }
    __syncthreads();

    if (role == 0) {
        // ---- q ----
        #pragma unroll
        for (int ct = 0; ct < 4; ++ct) {
            const int col = ct * 16 + ln;
            const __hip_bfloat16* wp = WbL + col * WSTR + quad * 8;
            short8 b0 = *(const short8*)(wp);
            short8 b1 = *(const short8*)(wp + 32);
            f32x4 c = {};
            c = mfma16(af0, b0, c);
            c = mfma16(af1, b1, c);
            const float bl = bq[col] * 0.125f;
            #pragma unroll
            for (int rr = 0; rr < 4; ++rr)
                qsb[(size_t)(R0 + rh * 16 + quad * 4 + rr) * HD + col] =
                    __float2bfloat16(c[rr] + bl);
        }
    } else if (role == 1) {
        // ---- k ----
        #pragma unroll
        for (int ct = 0; ct < 4; ++ct) {
            const int col = ct * 16 + ln;
            const __hip_bfloat16* wp = WbL + 64 * WSTR + col * WSTR + quad * 8;
            short8 b0 = *(const short8*)(wp);
            short8 b1 = *(const short8*)(wp + 32);
            f32x4 c = {};
            c = mfma16(af0, b0, c);
            c = mfma16(af1, b1, c);
            float tot = c[0] + c[1] + c[2] + c[3];
            tot += __shfl_xor(tot, 16);
            tot += __shfl_xor(tot, 32);
            if (quad == 0) kred[rh][col] = tot;
            const float bl = bk[col];
            #pragma unroll
            for (int rr = 0; rr < 4; ++rr)
                kT[col * 40 + rh * 16 + quad * 4 + rr] =
                    __float2bfloat16(c[rr] + bl);
        }
    } else if (role == 2) {
        // ---- v (main rows) ----
        #pragma unroll
        for (int ct = 0; ct < 4; ++ct) {
            const int col = ct * 16 + ln;
            const __hip_bfloat16* wp = WbL + 2 * 64 * WSTR + col * WSTR + quad * 8;
            short8 b0 = *(const short8*)(wp);
            short8 b1 = *(const short8*)(wp + 32);
            f32x4 c = {};
            c = mfma16(af0, b0, c);
            c = mfma16(af1, b1, c);
            float tot = c[0] + c[1] + c[2] + c[3];
            tot += __shfl_xor(tot, 16);
            tot += __shfl_xor(tot, 32);
            if (quad == 0) vred[rh][col] = tot;
            const float bl = bv[col];
            #pragma unroll
            for (int rr = 0; rr < 4; ++rr)
                vT[col * 40 + 2 + rh * 16 + quad * 4 + rr] =
                    __float2bfloat16(c[rr] + bl);
        }
    } else {
        // ---- v halo rows: rh0 -> t0-2,t0-1 (idx 0,1); rh1 -> t0+32,+33 (34,35)
        #pragma unroll
        for (int ct = 0; ct < 4; ++ct) {
            const int col = ct * 16 + ln;
            const __hip_bfloat16* wp = WbL + 2 * 64 * WSTR + col * WSTR + quad * 8;
            short8 b0 = *(const short8*)(wp);
            short8 b1 = *(const short8*)(wp + 32);
            f32x4 hc = {};
            hc = mfma16(af0, b0, hc);
            hc = mfma16(af1, b1, hc);
            if (quad == 0) {
                const float bl = bv[col];
                const int base = (rh == 0) ? 0 : 34;
                vT[col * 40 + base]     = __float2bfloat16(hflag ? hc[0] + bl : 0.f);
                vT[col * 40 + base + 1] = __float2bfloat16(hflag ? hc[1] + bl : 0.f);
            }
        }
    }
    __syncthreads();

    // column-sum partials (128 per batch)
    if (tid < 64) {
        kpart[(size_t)blockIdx.x * 64 + tid] =
            kred[0][tid] + kred[1][tid] + 32.f * bk[tid];
        vpart[(size_t)blockIdx.x * 64 + tid] =
            vred[0][tid] + vred[1][tid] + 32.f * bv[tid];
    }

    // locv5^T: thread (h, seg) -> 4 t's; window idx tl..tl+4 == t-2..t+2
    {
        const int h = tid & 63;
        const int tb = (tid >> 6) * 4;
        short4v u0 = *(const short4v*)&vT[h * 40 + tb];
        short4v u1 = *(const short4v*)&vT[h * 40 + tb + 4];
        float w[8];
        #pragma unroll
        for (int j = 0; j < 4; ++j) {
            w[j]     = sf(u0[j]);
            w[j + 4] = sf(u1[j]);
        }
        #pragma unroll
        for (int i = 0; i < 4; ++i)
            lvt[h * 40 + tb + i] =
                __float2bfloat16(w[i] + w[i+1] + w[i+2] + w[i+3] + w[i+4]);
    }

    // export edge k rows for mktot closed form (first 256 thr -> 256 entries)
    if (chunk == 0) {
        if (tid < 256) {
            const int t = tid >> 6, h = tid & 63;
            kedge[b * 512 + t * 64 + h] = b2f(kT[h * 40 + t]);
        }
    } else if (chunk == 127) {
        if (tid < 256) {
            const int t = tid >> 6, h = tid & 63;
            kedge[b * 512 + (4 + t) * 64 + h] = b2f(kT[h * 40 + 28 + t]);
        }
    }
    __syncthreads();

    // GEMM: M_chunk[h1][h2] = sum_t k[t][h1]*locv5[t][h2], K=32.
    // 16 output tiles / 8 waves = 2 MFMA per wave.
    {
        __hip_bfloat16* mp = Mpart + (size_t)(b * 128 + chunk) * 4096;
        const int strip = wv >> 1;          // h1-strip 0..3
        const int cth   = wv & 1;           // ct-half
        short8 a = *(const short8*)&kT[(strip * 16 + ln) * 40 + quad * 8];
        #pragma unroll
        for (int i = 0; i < 2; ++i) {
            const int ct = cth * 2 + i;
            short8 bb = *(const short8*)&lvt[(ct * 16 + ln) * 40 + quad * 8];
            f32x4 acc = {};
            acc = mfma16(a, bb, acc);
            #pragma unroll
            for (int rr = 0; rr < 4; ++rr)
                mp[(strip * 16 + quad * 4 + rr) * 64 + ct * 16 + ln] =
                    __float2bfloat16(acc[rr]);
        }
    }
}

// ---------------------------------------------------------------------------
// Kernel 2 (merged redprep + out): 1024 blocks x 128 thr, ALL co-resident
// (2048 waves << capacity -> spin-gate cannot deadlock).
// Phase A (xb<64): reduce 64 MTm elems over 128 Mpart chunks (2-wave split).
//         (xb==64): prep — ktot/Vtot from partials, mktot closed form, VDs.
//         Completion signalled via device-scope fetch_add on doneC[b].
// Gate: spin until doneC[b]==65, then device fence (acquire).
// Phase B: identical to the proven out_kernel body.
// ---------------------------------------------------------------------------
__global__ __launch_bounds__(128) void outred_kernel(
    const __hip_bfloat16* __restrict__ qsb, const __hip_bfloat16* __restrict__ Mpart,
    const float* __restrict__ kpart, const float* __restrict__ vpart,
    const float* __restrict__ kedge,
    __hip_bfloat16* __restrict__ MTm, float* __restrict__ mktotF,
    float* __restrict__ ktotF, float* __restrict__ VDs,
    float* __restrict__ VtotF, unsigned int* __restrict__ doneC,
    float* __restrict__ out)
{
    __shared__ float mred[64];
    __shared__ float red[2][64];
    __shared__ float red2[2][64];

    const int tid = threadIdx.x;
    const int wv = tid >> 6, lane = tid & 63;
    const int quad = lane >> 4, ln = lane & 15;
    const int R0 = blockIdx.x * 16;
    const int b = R0 >> 12;
    const int xb = blockIdx.x & 255;    // batch-local block index

    // early q fragment load (independent of the gate)
    short8 qa0, qa1;
    {
        const __hip_bfloat16* qp = qsb + (size_t)(R0 + ln) * HD + quad * 8;
        qa0 = *(const short8*)qp;
        qa1 = *(const short8*)(qp + 32);
    }

    // ======================= PHASE A =======================
    if (xb < 64) {
        // reduce MTm column xb: elem E = xb*64 + lane over 128 chunks
        const int E = xb * 64 + lane;
        const __hip_bfloat16* src =
            Mpart + ((size_t)b * 128 + wv * 64) * 4096 + E;
        float s = 0.f;
        #pragma unroll
        for (int c = 0; c < 64; ++c) s += b2f(src[(size_t)c * 4096]);
        if (wv == 1) mred[lane] = s;
        __syncthreads();
        if (wv == 0) {
            const float t = s + mred[lane];
            // E = h1*64 + h2 with h1 = xb, h2 = lane; MTm layout [h2][h1]
            MTm[(size_t)b * 4096 + lane * 64 + xb] =
                __float2bfloat16((EM1 * INVD5) * t);
        }
        if (tid == 0) {
            __threadfence();
            __hip_atomic_fetch_add(doneC + b, 1u, __ATOMIC_RELEASE,
                                   __HIP_MEMORY_SCOPE_AGENT);
        }
    } else if (xb == 64) {
        // prep: ktot/Vtot from partials + mktot closed form
        const int g = wv, hh = lane;
        float kp = 0.f, vp = 0.f;
        for (int j = 0; j < 64; ++j) {
            kp += kpart[(size_t)(b * 128 + g * 64 + j) * 64 + hh];
            vp += vpart[(size_t)(b * 128 + g * 64 + j) * 64 + hh];
        }
        red[g][hh] = kp;
        red2[g][hh] = vp;
        __syncthreads();
        if (tid < 64) {
            const float kt = red[0][hh] + red[1][hh];
            const float vt = red2[0][hh] + red2[1][hh];
            const float e0 = kedge[b * 512 + 0 * 64 + hh];
            const float e1 = kedge[b * 512 + 1 * 64 + hh];
            const float e2 = kedge[b * 512 + 2 * 64 + hh];
            const float e3 = kedge[b * 512 + 3 * 64 + hh];
            const float f0 = kedge[b * 512 + 4 * 64 + hh];
            const float f1 = kedge[b * 512 + 5 * 64 + hh];
            const float f2 = kedge[b * 512 + 6 * 64 + hh];
            const float f3 = kedge[b * 512 + 7 * 64 + hh];
            const float Sint = 5.f*kt - 4.f*e0 - 3.f*e1 - 2.f*e2 - e3
                             - f0 - 2.f*f1 - 3.f*f2 - 4.f*f3;
            const float SlocD = Sint * INVD5
                              + (e0+e1+e2 + f1+f2+f3) * INVD3
                              + (e0+e1+e2+e3 + f0+f1+f2+f3) * INVD4;
            mktotF[b * 64 + hh] = kt * (4092.f*INVD5 + 2.f*INVD4 + 2.f*INVD3)
                                + EM1 * SlocD;
            ktotF[b * 64 + hh]  = kt;
            VDs[b * 64 + hh]    = INVD5 * vt;
            VtotF[b * 64 + hh]  = vt;
        }
        if (tid == 0) {
            __threadfence();
            __hip_atomic_fetch_add(doneC + b, 1u, __ATOMIC_RELEASE,
                                   __HIP_MEMORY_SCOPE_AGENT);
        }
    }

    // ======================= GATE =======================
    if (tid == 0) {
        while (__hip_atomic_load(doneC + b, __ATOMIC_RELAXED,
                                 __HIP_MEMORY_SCOPE_AGENT) < 65u)
            __builtin_amdgcn_s_sleep(2);
    }
    __syncthreads();
    __threadfence();   // acquire: invalidate stale cached lines

    // ======================= PHASE B (= proven out_kernel) =================
    const __hip_bfloat16* mtb = MTm + (size_t)b * 4096;
    f32x4 acc[2];
    #pragma unroll
    for (int i = 0; i < 2; ++i) {
        const int ct = wv * 2 + i;
        short8 b0 = *(const short8*)(mtb + (ct * 16 + ln) * 64 + quad * 8);
        short8 b1 = *(const short8*)(mtb + (ct * 16 + ln) * 64 + 32 + quad * 8);
        f32x4 c = {};
        c = mfma16(qa0, b0, c);
        c = mfma16(qa1, b1, c);
        acc[i] = c;
    }

    // uniform-B fragments: every lane holds the same vector slice
    short8 mk0, mk1, kt0, kt1;
    #pragma unroll
    for (int j = 0; j < 8; ++j) {
        mk0[j] = bfs(mktotF[b * 64 + quad * 8 + j]);
        mk1[j] = bfs(mktotF[b * 64 + 32 + quad * 8 + j]);
        kt0[j] = bfs(ktotF[b * 64 + quad * 8 + j]);
        kt1[j] = bfs(ktotF[b * 64 + 32 + quad * 8 + j]);
    }
    f32x4 accd = {}, acck = {};
    accd = mfma16(qa0, mk0, accd);
    accd = mfma16(qa1, mk1, accd);     // den per row (lane-uniform)
    acck = mfma16(qa0, kt0, acck);
    acck = mfma16(qa1, kt1, acck);     // qs·ktot per row

    float vt[2], vd[2];
    #pragma unroll
    for (int i = 0; i < 2; ++i) {
        const int ct = wv * 2 + i;
        vt[i] = VtotF[b * 64 + ct * 16 + ln];
        vd[i] = VDs[b * 64 + ct * 16 + ln];
    }

    float inv[4];
    #pragma unroll
    for (int r = 0; r < 4; ++r) inv[r] = 1.f / (4096.f + accd[r]);

    #pragma unroll
    for (int i = 0; i < 2; ++i)
        #pragma unroll
        for (int r = 0; r < 4; ++r)
            out[(size_t)(R0 + quad * 4 + r) * HD + (wv * 2 + i) * 16 + ln] =
                (vt[i] + acc[i][r] + acck[r] * vd[i]) * inv[r];
}

// ---------------------------------------------------------------------------
extern "C" void kernel_launch(void* const* d_in, const int* in_sizes, int n_in,
                              void* d_out, int out_size, void* d_ws, size_t ws_size,
                              hipStream_t stream)
{
    const float* feat = (const float*)d_in[0];
    const float* Wq = (const float*)d_in[1];
    const float* bq = (const float*)d_in[2];
    const float* Wk = (const float*)d_in[3];
    const float* bk = (const float*)d_in[4];
    const float* Wv = (const float*)d_in[5];
    const float* bv = (const float*)d_in[6];
    float* out = (float*)d_out;

    char* ws = (char*)d_ws;
    __hip_bfloat16* qsb    = (__hip_bfloat16*)(ws + 0);                  // 2 MB
    __hip_bfloat16* Mpart  = (__hip_bfloat16*)(ws + (2u << 20));         // 4 MB
    float*          kpart  = (float*)(ws + (6u << 20));                  // 128 KB
    float*          vpart  = (float*)(ws + (6u << 20) + 131072);         // 128 KB
    float*          kedge  = (float*)(ws + (6u << 20) + 262144);         // 8 KB
    __hip_bfloat16* MTm    = (__hip_bfloat16*)(ws + (6u << 20) + 270336);// 32 KB
    float*          mktotF = (float*)(ws + (6u << 20) + 303104);         // 1 KB
    float*          ktotF  = (float*)(ws + (6u << 20) + 304128);         // 1 KB
    float*          VDs    = (float*)(ws + (6u << 20) + 305152);         // 1 KB
    float*          VtotF  = (float*)(ws + (6u << 20) + 306176);         // 1 KB
    unsigned int*   doneC  = (unsigned int*)(ws + (6u << 20) + 307200);  // 16 B

    projm_kernel<<<dim3(512), dim3(512), 0, stream>>>(
        feat, Wq, Wk, Wv, bq, bk, bv, qsb, kpart, vpart, Mpart, kedge, doneC);
    outred_kernel<<<dim3(1024), dim3(128), 0, stream>>>(
        qsb, Mpart, kpart, vpart, kedge, MTm, mktotF, ktotF, VDs, VtotF,
        doneC, out);
}